// Round 1
// baseline (11136.554 us; speedup 1.0000x reference)
//
#include <hip/hip_runtime.h>
#include <hip/hip_bf16.h>

using f4 = __attribute__((ext_vector_type(4))) float;

#define D 128
#define D4 32

__global__ void degree_kernel(const int* __restrict__ dst, int E, unsigned int* __restrict__ deg) {
    int stride = gridDim.x * blockDim.x;
    for (int e = blockIdx.x * blockDim.x + threadIdx.x; e < E; e += stride)
        atomicAdd(&deg[dst[e]], 1u);
}

__global__ void dinv_kernel(const unsigned int* __restrict__ deg, float* __restrict__ dinv, int N) {
    int i = blockIdx.x * blockDim.x + threadIdx.x;
    if (i < N) dinv[i] = 1.0f / sqrtf((float)(deg[i] + 1u));
}

// G = (X @ W) * dinv[row]   (scale folded into epilogue)
// block = 256 threads, 32 rows/block, thread t: rows (t>>5)*4.., cols (t&31)*4..
__global__ void gemm_scaled(const float* __restrict__ X, const float* __restrict__ W,
                            const float* __restrict__ dinv, float* __restrict__ G, int N) {
    __shared__ float Ws[D * D];  // 64 KB
    int tid = threadIdx.x;
    for (int i = tid; i < D * D / 4; i += 256)
        ((f4*)Ws)[i] = ((const f4*)W)[i];
    __syncthreads();

    int row0 = blockIdx.x * 32 + (tid >> 5) * 4;
    int c0 = (tid & 31) * 4;
    // clamp rows for (possible) tail block; stores are guarded
    int r_idx[4];
#pragma unroll
    for (int r = 0; r < 4; ++r) r_idx[r] = (row0 + r < N) ? (row0 + r) : (N - 1);

    f4 acc[4] = {};
    for (int k = 0; k < D; k += 4) {
        f4 xv[4], wv[4];
#pragma unroll
        for (int r = 0; r < 4; ++r)
            xv[r] = *(const f4*)(X + (size_t)r_idx[r] * D + k);
#pragma unroll
        for (int kk = 0; kk < 4; ++kk)
            wv[kk] = *(const f4*)(Ws + (k + kk) * D + c0);
#pragma unroll
        for (int r = 0; r < 4; ++r)
#pragma unroll
            for (int kk = 0; kk < 4; ++kk)
                acc[r] += xv[r][kk] * wv[kk];
    }
#pragma unroll
    for (int r = 0; r < 4; ++r) {
        if (row0 + r < N) {
            f4 out = acc[r] * dinv[row0 + r];
            *(f4*)(G + (size_t)(row0 + r) * D + c0) = out;
        }
    }
}

// tmp[dst[e]][:] += g[src[e]][:]  — one edge per 32 lanes, float4 per lane
__global__ void scatter_kernel(const float* __restrict__ g, const int* __restrict__ src,
                               const int* __restrict__ dst, float* __restrict__ tmp, int E) {
    int lane = threadIdx.x & 31;
    int grp = (blockIdx.x * blockDim.x + threadIdx.x) >> 5;
    int ngrp = (gridDim.x * blockDim.x) >> 5;
    for (int e = grp; e < E; e += ngrp) {
        int s = src[e], d = dst[e];
        f4 v = ((const f4*)(g + (size_t)s * D))[lane];
        float* o = tmp + (size_t)d * D + lane * 4;
        unsafeAtomicAdd(o + 0, v[0]);
        unsafeAtomicAdd(o + 1, v[1]);
        unsafeAtomicAdd(o + 2, v[2]);
        unsafeAtomicAdd(o + 3, v[3]);
    }
}

// out = dinv[row] * (tmp + g) + b, optional ReLU. Elementwise (f4 granularity).
template <bool RELU>
__global__ void finalize_kernel(const float* __restrict__ tmp, const float* __restrict__ gbuf,
                                const float* __restrict__ dinv, const float* __restrict__ b,
                                float* __restrict__ out, int N) {
    int total = N * D4;
    int stride = gridDim.x * blockDim.x;
    for (int i = blockIdx.x * blockDim.x + threadIdx.x; i < total; i += stride) {
        int row = i >> 5;
        int cb = i & 31;
        f4 t = ((const f4*)tmp)[i];
        f4 gg = ((const f4*)gbuf)[i];
        f4 bb = ((const f4*)b)[cb];
        f4 v = dinv[row] * (t + gg) + bb;
        if (RELU) {
#pragma unroll
            for (int j = 0; j < 4; ++j) v[j] = fmaxf(v[j], 0.0f);
        }
        ((f4*)out)[i] = v;
    }
}

__global__ void decode_kernel(const float* __restrict__ z, const int* __restrict__ s,
                              const int* __restrict__ d, float* __restrict__ out, int P) {
    int lane = threadIdx.x & 31;
    int grp = (blockIdx.x * blockDim.x + threadIdx.x) >> 5;
    int ngrp = (gridDim.x * blockDim.x) >> 5;
    for (int e = grp; e < P; e += ngrp) {
        f4 a = ((const f4*)(z + (size_t)s[e] * D))[lane];
        f4 b = ((const f4*)(z + (size_t)d[e] * D))[lane];
        float dot = a[0] * b[0] + a[1] * b[1] + a[2] * b[2] + a[3] * b[3];
#pragma unroll
        for (int off = 16; off >= 1; off >>= 1)
            dot += __shfl_xor(dot, off);
        if (lane == 0) out[e] = dot;
    }
}

extern "C" void kernel_launch(void* const* d_in, const int* in_sizes, int n_in,
                              void* d_out, int out_size, void* d_ws, size_t ws_size,
                              hipStream_t stream) {
    const float* x  = (const float*)d_in[0];
    const float* W1 = (const float*)d_in[1];
    const float* b1 = (const float*)d_in[2];
    const float* W2 = (const float*)d_in[3];
    const float* b2 = (const float*)d_in[4];
    const int*   ei = (const int*)d_in[5];
    const int*   pe = (const int*)d_in[6];
    const int*   ne = (const int*)d_in[7];

    int N  = in_sizes[0] / D;
    int E  = in_sizes[5] / 2;
    int P  = in_sizes[6] / 2;
    int Pn = in_sizes[7] / 2;
    const int* src = ei;
    const int* dst = ei + E;

    char* ws = (char*)d_ws;
    unsigned int* deg = (unsigned int*)ws;            // N uints
    float* dinv = (float*)(ws + (512 << 10));         // N floats
    float* bufA = (float*)(ws + (1 << 20));           // N*D floats (51.2 MB)

    float* out = (float*)d_out;
    float* pos = out;
    float* neg = out + P;
    float* z   = out + P + Pn;                        // N*D floats in d_out

    // degree + dinv (shared by both layers)
    hipMemsetAsync(deg, 0, (size_t)N * sizeof(unsigned int), stream);
    degree_kernel<<<2048, 256, 0, stream>>>(dst, E, deg);
    dinv_kernel<<<(N + 255) / 256, 256, 0, stream>>>(deg, dinv, N);

    // ---- layer 1: g1 = (x@W1)*dinv in bufA; tmp1 in z-region ----
    gemm_scaled<<<(N + 31) / 32, 256, 0, stream>>>(x, W1, dinv, bufA, N);
    hipMemsetAsync(z, 0, (size_t)N * D * sizeof(float), stream);
    scatter_kernel<<<4096, 256, 0, stream>>>(bufA, src, dst, z, E);
    // a1 = relu(dinv*(tmp1+g1)+b1) -> bufA (in place)
    finalize_kernel<true><<<2048, 256, 0, stream>>>(z, bufA, dinv, b1, bufA, N);

    // ---- layer 2: g2 = (a1@W2)*dinv in z-region; tmp2 in bufA ----
    gemm_scaled<<<(N + 31) / 32, 256, 0, stream>>>(bufA, W2, dinv, z, N);
    hipMemsetAsync(bufA, 0, (size_t)N * D * sizeof(float), stream);
    scatter_kernel<<<4096, 256, 0, stream>>>(z, src, dst, bufA, E);
    // z = dinv*(tmp2+g2)+b2 -> z (in place)
    finalize_kernel<false><<<2048, 256, 0, stream>>>(bufA, z, dinv, b2, z, N);

    // ---- decode ----
    decode_kernel<<<2048, 256, 0, stream>>>(z, pe, pe + P, pos, P);
    decode_kernel<<<2048, 256, 0, stream>>>(z, ne, ne + Pn, neg, Pn);
}

// Round 2
// 1080.439 us; speedup vs baseline: 10.3074x; 10.3074x over previous
//
#include <hip/hip_runtime.h>
#include <hip/hip_bf16.h>

using f4 = __attribute__((ext_vector_type(4))) float;

#define D 128
#define SCHUNK 32

__global__ void degree_kernel(const int* __restrict__ dst, int E, unsigned int* __restrict__ deg) {
    int stride = gridDim.x * blockDim.x;
    for (int e = blockIdx.x * blockDim.x + threadIdx.x; e < E; e += stride)
        atomicAdd(&deg[dst[e]], 1u);
}

__global__ void dinv_kernel(const unsigned int* __restrict__ deg, float* __restrict__ dinv, int N) {
    int i = blockIdx.x * blockDim.x + threadIdx.x;
    if (i < N) dinv[i] = 1.0f / sqrtf((float)(deg[i] + 1u));
}

// ---- 3-kernel exclusive scan of deg -> offs (and cursor copy) ----
__global__ void scan_partial(const unsigned int* __restrict__ deg, unsigned int* __restrict__ tsum,
                             int N, int T) {
    int t = blockIdx.x * blockDim.x + threadIdx.x;
    if (t >= T) return;
    int i0 = t * SCHUNK, i1 = min(i0 + SCHUNK, N);
    unsigned int s = 0;
    for (int i = i0; i < i1; ++i) s += deg[i];
    tsum[t] = s;
}

// single block of 1024 threads; turns tsum into exclusive bases; writes offs[N]=E
__global__ void scan_tsum(unsigned int* __restrict__ tsum, int* __restrict__ offs, int N, int T) {
    __shared__ unsigned int sd[1024];
    int tid = threadIdx.x;
    unsigned int v[4], part = 0;
#pragma unroll
    for (int j = 0; j < 4; ++j) {
        int t = tid * 4 + j;
        v[j] = (t < T) ? tsum[t] : 0u;
        part += v[j];
    }
    sd[tid] = part;
    __syncthreads();
    for (int off = 1; off < 1024; off <<= 1) {
        unsigned int u = (tid >= off) ? sd[tid - off] : 0u;
        __syncthreads();
        sd[tid] += u;
        __syncthreads();
    }
    unsigned int base = sd[tid] - part;  // exclusive over threads
#pragma unroll
    for (int j = 0; j < 4; ++j) {
        int t = tid * 4 + j;
        if (t < T) tsum[t] = base;
        base += v[j];
    }
    if (tid == 1023) offs[N] = (int)sd[1023];
}

__global__ void scan_final(const unsigned int* __restrict__ deg, const unsigned int* __restrict__ tsum,
                           int* __restrict__ offs, int* __restrict__ cursor, int N, int T) {
    int t = blockIdx.x * blockDim.x + threadIdx.x;
    if (t >= T) return;
    unsigned int run = tsum[t];
    int i0 = t * SCHUNK, i1 = min(i0 + SCHUNK, N);
    for (int i = i0; i < i1; ++i) {
        offs[i] = (int)run;
        cursor[i] = (int)run;
        run += deg[i];
    }
}

__global__ void fill_kernel(const int* __restrict__ src, const int* __restrict__ dst,
                            int* __restrict__ cursor, int* __restrict__ csr_src, int E) {
    int stride = gridDim.x * blockDim.x;
    for (int e = blockIdx.x * blockDim.x + threadIdx.x; e < E; e += stride) {
        int d = dst[e];
        int pos = atomicAdd(&cursor[d], 1);
        csr_src[pos] = src[e];
    }
}

// G = (X @ W) * dinv[row]
__global__ void gemm_scaled(const float* __restrict__ X, const float* __restrict__ W,
                            const float* __restrict__ dinv, float* __restrict__ G, int N) {
    __shared__ float Ws[D * D];  // 64 KB
    int tid = threadIdx.x;
    for (int i = tid; i < D * D / 4; i += 256)
        ((f4*)Ws)[i] = ((const f4*)W)[i];
    __syncthreads();

    int row0 = blockIdx.x * 32 + (tid >> 5) * 4;
    int c0 = (tid & 31) * 4;
    int r_idx[4];
#pragma unroll
    for (int r = 0; r < 4; ++r) r_idx[r] = (row0 + r < N) ? (row0 + r) : (N - 1);

    f4 acc[4] = {};
    for (int k = 0; k < D; k += 4) {
        f4 xv[4], wv[4];
#pragma unroll
        for (int r = 0; r < 4; ++r)
            xv[r] = *(const f4*)(X + (size_t)r_idx[r] * D + k);
#pragma unroll
        for (int kk = 0; kk < 4; ++kk)
            wv[kk] = *(const f4*)(Ws + (k + kk) * D + c0);
#pragma unroll
        for (int r = 0; r < 4; ++r)
#pragma unroll
            for (int kk = 0; kk < 4; ++kk)
                acc[r] += xv[r][kk] * wv[kk];
    }
#pragma unroll
    for (int r = 0; r < 4; ++r) {
        if (row0 + r < N) {
            f4 out = acc[r] * dinv[row0 + r];
            *(f4*)(G + (size_t)(row0 + r) * D + c0) = out;
        }
    }
}

// out[n] = dinv[n] * (sum_{e: dst=n} g[src[e]] + g[n]) + b   (+ReLU)
// 32 lanes per node, f4 per lane.
template <bool RELU>
__global__ void aggregate_kernel(const float* __restrict__ g, const int* __restrict__ csr_src,
                                 const int* __restrict__ offs, const float* __restrict__ dinv,
                                 const float* __restrict__ bias, float* __restrict__ out, int N) {
    int lane = threadIdx.x & 31;
    int n = (blockIdx.x * blockDim.x + threadIdx.x) >> 5;
    if (n >= N) return;
    int e0 = offs[n], e1 = offs[n + 1];

    f4 acc = ((const f4*)(g + (size_t)n * D))[lane];  // self loop
    for (int e = e0; e < e1; e += 32) {
        int rem = e1 - e;
        int sj = 0;
        if (lane < rem) sj = csr_src[e + lane];
        int cnt = rem < 32 ? rem : 32;
        for (int k = 0; k < cnt; ++k) {
            int s = __shfl(sj, k, 32);
            acc += ((const f4*)(g + (size_t)s * D))[lane];
        }
    }
    f4 bb = ((const f4*)bias)[lane];
    f4 v = dinv[n] * acc + bb;
    if (RELU) {
#pragma unroll
        for (int j = 0; j < 4; ++j) v[j] = fmaxf(v[j], 0.0f);
    }
    ((f4*)(out + (size_t)n * D))[lane] = v;
}

__global__ void decode_kernel(const float* __restrict__ z, const int* __restrict__ s,
                              const int* __restrict__ d, float* __restrict__ out, int P) {
    int lane = threadIdx.x & 31;
    int grp = (blockIdx.x * blockDim.x + threadIdx.x) >> 5;
    int ngrp = (gridDim.x * blockDim.x) >> 5;
    for (int e = grp; e < P; e += ngrp) {
        f4 a = ((const f4*)(z + (size_t)s[e] * D))[lane];
        f4 b = ((const f4*)(z + (size_t)d[e] * D))[lane];
        float dot = a[0] * b[0] + a[1] * b[1] + a[2] * b[2] + a[3] * b[3];
#pragma unroll
        for (int off = 16; off >= 1; off >>= 1)
            dot += __shfl_xor(dot, off);
        if (lane == 0) out[e] = dot;
    }
}

extern "C" void kernel_launch(void* const* d_in, const int* in_sizes, int n_in,
                              void* d_out, int out_size, void* d_ws, size_t ws_size,
                              hipStream_t stream) {
    const float* x  = (const float*)d_in[0];
    const float* W1 = (const float*)d_in[1];
    const float* b1 = (const float*)d_in[2];
    const float* W2 = (const float*)d_in[3];
    const float* b2 = (const float*)d_in[4];
    const int*   ei = (const int*)d_in[5];
    const int*   pe = (const int*)d_in[6];
    const int*   ne = (const int*)d_in[7];

    int N  = in_sizes[0] / D;
    int E  = in_sizes[5] / 2;
    int P  = in_sizes[6] / 2;
    int Pn = in_sizes[7] / 2;
    const int* src = ei;
    const int* dst = ei + E;
    int T = (N + SCHUNK - 1) / SCHUNK;

    char* ws = (char*)d_ws;
    unsigned int* deg    = (unsigned int*)(ws);                 // 400 KB
    float*        dinv   = (float*)(ws + 0x80000);              // 400 KB
    unsigned int* tsum   = (unsigned int*)(ws + 0x100000);      // 12.5 KB
    int*          offs   = (int*)(ws + 0x110000);               // (N+1)*4
    int*          cursor = (int*)(ws + 0x190000);               // 400 KB
    int*          csr    = (int*)(ws + 0x210000);               // E*4 = 12.8 MB
    float*        bufA   = (float*)(ws + 0xF10000);             // N*D*4 = 51.2 MB

    float* out = (float*)d_out;
    float* pos = out;
    float* neg = out + P;
    float* z   = out + P + Pn;  // N*D floats

    // ---- graph preprocessing (once, reused by both layers) ----
    hipMemsetAsync(deg, 0, (size_t)N * sizeof(unsigned int), stream);
    degree_kernel<<<2048, 256, 0, stream>>>(dst, E, deg);
    dinv_kernel<<<(N + 255) / 256, 256, 0, stream>>>(deg, dinv, N);
    scan_partial<<<(T + 255) / 256, 256, 0, stream>>>(deg, tsum, N, T);
    scan_tsum<<<1, 1024, 0, stream>>>(tsum, offs, N, T);
    scan_final<<<(T + 255) / 256, 256, 0, stream>>>(deg, tsum, offs, cursor, N, T);
    fill_kernel<<<2048, 256, 0, stream>>>(src, dst, cursor, csr, E);

    int agg_blocks = (N + 7) / 8;  // 256 thr = 8 nodes/block

    // ---- layer 1 ----
    gemm_scaled<<<(N + 31) / 32, 256, 0, stream>>>(x, W1, dinv, bufA, N);
    aggregate_kernel<true><<<agg_blocks, 256, 0, stream>>>(bufA, csr, offs, dinv, b1, z, N);

    // ---- layer 2 ----
    gemm_scaled<<<(N + 31) / 32, 256, 0, stream>>>(z, W2, dinv, bufA, N);
    aggregate_kernel<false><<<agg_blocks, 256, 0, stream>>>(bufA, csr, offs, dinv, b2, z, N);

    // ---- decode ----
    decode_kernel<<<2048, 256, 0, stream>>>(z, pe, pe + P, pos, P);
    decode_kernel<<<2048, 256, 0, stream>>>(z, ne, ne + Pn, neg, Pn);
}